// Round 16
// baseline (131.963 us; speedup 1.0000x reference)
//
#include <hip/hip_runtime.h>
#include <hip/hip_bf16.h>
#include <stdint.h>

typedef unsigned short u16;
typedef __attribute__((ext_vector_type(8))) short bf16x8;
typedef __attribute__((ext_vector_type(4))) float f32x4;
typedef __attribute__((ext_vector_type(16))) float f32x16;

#define NR 8192     // B*L rows
#define DM 512      // model dim
#define NH 8
#define HD 64
#define LQ 1024

// fold 1/sqrt(64) * log2(e) into LN-q so scores are in exp2 domain
#define QSCALE (0.125f * 1.4426950408889634f)
// fixed softmax offset (safe: |s| <= 512*0.125*log2e = 92 by Cauchy-Schwarz)
#define SOFF 16.0f

// async global->LDS 16B copy; LDS dest must be wave-uniform base + lane*16
// (our unit layout satisfies this). Correctness HW-verified in round 11.
#define GLOAD16(g, l) __builtin_amdgcn_global_load_lds(                     \
    (const __attribute__((address_space(1))) void*)(g),                     \
    (__attribute__((address_space(3))) void*)(l), 16, 0, 0)

__device__ __forceinline__ u16 f2b(float f) {
    union { float f; uint32_t u; } v; v.f = f;
    uint32_t r = v.u + 0x7fffu + ((v.u >> 16) & 1u);   // RNE
    return (u16)(r >> 16);
}
// packed f32x2 -> bf16x2 (v_cvt_pk_bf16_f32, RNE)
__device__ __forceinline__ uint32_t pk2(float lo, float hi) {
    __hip_bfloat162 h = __float22bfloat162_rn(make_float2(lo, hi));
    union { __hip_bfloat162 h; uint32_t u; } c; c.h = h;
    return c.u;
}
__device__ __forceinline__ float b2f(uint32_t lo16) {
    union { uint32_t u; float f; } c; c.u = lo16 << 16; return c.f;
}

// ---------------------------------------------------------------------------
// prep: fused conv3 (blocks 0..6143) + wt5 transpose (blocks 6144..6463)
// ---------------------------------------------------------------------------
__global__ __launch_bounds__(256)
void prep_kernel(const float* __restrict__ q, const float* __restrict__ k,
                 const float* __restrict__ v, u16* __restrict__ qo,
                 u16* __restrict__ ko, u16* __restrict__ vo,
                 const float* __restrict__ W0, const float* __restrict__ W1,
                 const float* __restrict__ W2, const float* __restrict__ W3,
                 const float* __restrict__ W4,
                 u16* __restrict__ T0, u16* __restrict__ T1, u16* __restrict__ T2,
                 u16* __restrict__ T3, u16* __restrict__ T4)
{
    __shared__ float S[64][65];
    const int bid = blockIdx.x;
    if (bid < 6144) {
        const int y = bid >> 11, x = bid & 2047;
        const float* in = y == 0 ? q : y == 1 ? k : v;
        u16* out = y == 0 ? qo : y == 1 ? ko : vo;
        const int i = x * 256 + threadIdx.x;
        const float4* p = (const float4*)in + (size_t)i * 2;
        float4 a = p[0], b = p[1];
        uint4 o;
        o.x = pk2(a.x, a.y);
        o.y = pk2(a.z, a.w);
        o.z = pk2(b.x, b.y);
        o.w = pk2(b.z, b.w);
        ((uint4*)out)[i] = o;
    } else {
        const int id = bid - 6144;
        const int z = id >> 6, idx = id & 63;
        const float* W = z == 0 ? W0 : z == 1 ? W1 : z == 2 ? W2 : z == 3 ? W3 : W4;
        u16* Wt = z == 0 ? T0 : z == 1 ? T1 : z == 2 ? T2 : z == 3 ? T3 : T4;
        const int k0 = (idx >> 3) * 64, n0 = (idx & 7) * 64;
        #pragma unroll
        for (int p = 0; p < 16; ++p) {
            int i = threadIdx.x + p * 256;
            int r = i >> 6, c = i & 63;
            S[r][c] = W[(size_t)(k0 + r) * DM + n0 + c];
        }
        __syncthreads();
        #pragma unroll
        for (int p = 0; p < 16; ++p) {
            int i = threadIdx.x + p * 256;
            int r = i >> 6, c = i & 63;
            Wt[(size_t)(n0 + r) * DM + k0 + c] = f2b(S[c][r]);
        }
    }
}

// ---------------------------------------------------------------------------
// ln_all (round-10 verified): blocks 0..16383 row LN q/k; 16384..16511
// v LN + per-head transpose -> vtb[b][h][d][l].
// ---------------------------------------------------------------------------
__global__ __launch_bounds__(256)
void ln_all_kernel(const float* __restrict__ res, const u16* __restrict__ kpb,
                   const u16* __restrict__ vpb,
                   const float* __restrict__ gq, const float* __restrict__ bq,
                   const float* __restrict__ gk, const float* __restrict__ bk,
                   const float* __restrict__ gv, const float* __restrict__ bv,
                   u16* __restrict__ oq, u16* __restrict__ ok,
                   u16* __restrict__ vtb)
{
    __shared__ float ss[4], ss2[4];
    __shared__ u16 S[64][82];
    __shared__ float stats[64][2];
    __shared__ float gb_[512], bb_[512];

    const int bid = blockIdx.x;
    const int t = threadIdx.x;

    if (bid < 16384) {
        const int y = bid >> 13;            // 0=q, 1=k
        const int row = bid & 8191;
        const float* gm = y == 0 ? gq : gk;
        const float* be = y == 0 ? bq : bk;
        u16* out = y == 0 ? oq : ok;
        const float scale = y == 0 ? QSCALE : 1.f;

        const size_t off = (size_t)row * DM + t * 2;
        float vx, vy;
        if (y == 0) {
            float2 v = *(const float2*)(res + off);
            vx = v.x; vy = v.y;
        } else {
            uint32_t u = *(const uint32_t*)(kpb + off);
            vx = b2f(u & 0xffffu); vy = b2f(u >> 16);
        }
        float s = vx + vy, s2 = vx * vx + vy * vy;
        #pragma unroll
        for (int o = 32; o; o >>= 1) { s += __shfl_down(s, o); s2 += __shfl_down(s2, o); }
        if ((t & 63) == 0) { ss[t >> 6] = s; ss2[t >> 6] = s2; }
        __syncthreads();
        float Sm = ss[0] + ss[1] + ss[2] + ss[3];
        float S2m = ss2[0] + ss2[1] + ss2[2] + ss2[3];
        float mu = Sm * (1.f / DM);
        float var = S2m * (1.f / DM) - mu * mu;
        float rs = rsqrtf(var + 1e-6f);
        float g0 = gm[t * 2] * scale, g1 = gm[t * 2 + 1] * scale;
        float b0 = be[t * 2] * scale, b1 = be[t * 2 + 1] * scale;
        float o0 = (vx - mu) * rs * g0 + b0;
        float o1 = (vy - mu) * rs * g1 + b1;
        *(uint32_t*)(out + off) = pk2(o0, o1);
        return;
    }

    // ---- v LN + transpose tile
    const int id = bid - 16384;
    const int lt = id & 15, b = id >> 4;

    gb_[t]       = gv[t];
    gb_[t + 256] = gv[t + 256];
    bb_[t]       = bv[t];
    bb_[t + 256] = bv[t + 256];

    // phase 1: row stats (4 lanes per row, interleaved 32-col chunks)
    {
        const int r = t >> 2, qd = t & 3;
        const u16* src = vpb + ((size_t)(b * LQ + lt * 64 + r)) * DM + qd * 8;
        float s = 0.f, s2 = 0.f;
        #pragma unroll
        for (int p = 0; p < 16; ++p) {
            uint4 x = *(const uint4*)(src + p * 32);
            const uint32_t xs[4] = {x.x, x.y, x.z, x.w};
            #pragma unroll
            for (int e = 0; e < 4; ++e) {
                float f0 = b2f(xs[e] & 0xffffu), f1 = b2f(xs[e] >> 16);
                s += f0 + f1; s2 += f0 * f0 + f1 * f1;
            }
        }
        s  += __shfl_xor(s, 1);  s  += __shfl_xor(s, 2);
        s2 += __shfl_xor(s2, 1); s2 += __shfl_xor(s2, 2);
        if (qd == 0) {
            float mu = s * (1.f / DM);
            float var = s2 * (1.f / DM) - mu * mu;
            stats[r][0] = mu;
            stats[r][1] = rsqrtf(var + 1e-6f);
        }
    }
    __syncthreads();

    // phase 2: per head, normalize into S then transpose-write to vtb
    for (int h = 0; h < NH; ++h) {
        {
            const int rr = t >> 2, dc = (t & 3) * 16;
            const u16* sp = vpb + ((size_t)(b * LQ + lt * 64 + rr)) * DM + h * 64 + dc;
            uint4 a = *(const uint4*)sp;
            uint4 b4 = *(const uint4*)(sp + 8);
            const float mu = stats[rr][0], rs = stats[rr][1];
            const uint32_t xs[8] = {a.x, a.y, a.z, a.w, b4.x, b4.y, b4.z, b4.w};
            #pragma unroll
            for (int e = 0; e < 8; ++e) {
                const int c = h * 64 + dc + e * 2;
                float f0 = (b2f(xs[e] & 0xffffu) - mu) * rs * gb_[c]     + bb_[c];
                float f1 = (b2f(xs[e] >> 16)     - mu) * rs * gb_[c + 1] + bb_[c + 1];
                *(uint32_t*)&S[rr][dc + e * 2] = pk2(f0, f1);
            }
        }
        __syncthreads();
        {
            const int d = t >> 2, lc = (t & 3) * 16;
            u16 tmp[16];
            #pragma unroll
            for (int e = 0; e < 16; ++e) tmp[e] = S[lc + e][d];
            u16* dst = vtb + (((size_t)(b * NH + h) * HD + d) << 10) + lt * 64 + lc;
            *(uint4*)dst       = *(uint4*)&tmp[0];
            *(uint4*)(dst + 8) = *(uint4*)&tmp[8];
        }
        __syncthreads();
    }
}

// ---------------------------------------------------------------------------
// bf16 MFMA GEMM body, m97 structure: 128x128 tile, 512 threads = 8 waves,
// A and B staged via global_load_lds width=16 (direct-to-LDS; m151: +35%
// vs reg-staging at this tile). bf16 inputs only. LDS dest = wave-uniform
// base + lane*16. Latency hidden by 4 blocks/CU co-residency (m114).
// ---------------------------------------------------------------------------
template<bool RELU, bool OUT_BF16>
__device__ __forceinline__
void gemm_body(const u16* __restrict__ A, const u16* __restrict__ Bt,
               const float* __restrict__ bias, void* __restrict__ Cout)
{
    __shared__ u16 Al[4 * 128 * 8];
    __shared__ u16 Bl[4 * 128 * 8];
    const int t = threadIdx.x;
    const int w = t >> 6, l = t & 63;
    const int m0 = blockIdx.x * 128, n0 = blockIdx.y * 128;
    const int sg = w & 3, sr = (w >> 2) * 64;
    const int wm = w >> 2, wn = w & 3;

    const u16* Ap = A  + (size_t)(m0 + sr + l) * DM + sg * 8;
    const u16* Bp = Bt + (size_t)(n0 + sr + l) * DM + sg * 8;
    u16* Alp = &Al[(sg * 128 + sr + l) * 8];
    u16* Blp = &Bl[(sg * 128 + sr + l) * 8];

    f32x4 acc[4][2];
    #pragma unroll
    for (int mi = 0; mi < 4; ++mi)
        #pragma unroll
        for (int ni = 0; ni < 2; ++ni)
            acc[mi][ni] = {0.f, 0.f, 0.f, 0.f};

    for (int kb = 0; kb < DM / 32; ++kb) {
        __syncthreads();                // prior frag reads done
        GLOAD16(Ap + kb * 32, Alp);
        GLOAD16(Bp + kb * 32, Blp);
        __syncthreads();                // vmcnt drain -> tile visible
        bf16x8 af[4], bfr[2];
        #pragma unroll
        for (int mi = 0; mi < 4; ++mi)
            af[mi] = *(const bf16x8*)&Al[((l >> 4) * 128 + wm * 64 + mi * 16 + (l & 15)) * 8];
        #pragma unroll
        for (int ni = 0; ni < 2; ++ni)
            bfr[ni] = *(const bf16x8*)&Bl[((l >> 4) * 128 + wn * 32 + ni * 16 + (l & 15)) * 8];
        #pragma unroll
        for (int mi = 0; mi < 4; ++mi)
            #pragma unroll
            for (int ni = 0; ni < 2; ++ni)
                acc[mi][ni] = __builtin_amdgcn_mfma_f32_16x16x32_bf16(af[mi], bfr[ni], acc[mi][ni], 0, 0, 0);
    }

    const int cq = l >> 4, cr = l & 15;
    #pragma unroll
    for (int mi = 0; mi < 4; ++mi) {
        const int row = m0 + wm * 64 + mi * 16 + cq * 4;
        #pragma unroll
        for (int ni = 0; ni < 2; ++ni) {
            const int col = n0 + wn * 32 + ni * 16 + cr;
            const float bb = bias[col];
            #pragma unroll
            for (int j = 0; j < 4; ++j) {
                float vv = acc[mi][ni][j] + bb;
                if (RELU) vv = fmaxf(vv, 0.f);
                if (OUT_BF16) ((u16*)Cout)[(size_t)(row + j) * DM + col] = f2b(vv);
                else          ((float*)Cout)[(size_t)(row + j) * DM + col] = vv;
            }
        }
    }
}

template<bool RELU, bool OUT_BF16>
__global__ __launch_bounds__(512)
void mfma_gemm_kernel(const u16* __restrict__ A, const u16* __restrict__ Bt,
                      const float* __restrict__ bias, void* __restrict__ Cout)
{
    gemm_body<RELU, OUT_BF16>(A, Bt, bias, Cout);
}

// ---------------------------------------------------------------------------
// fused q/k/v projection GEMM, grid (64, 4, 3), GLOAD16 body, bf16 A.
// q writes f32 res (residual output); k/v write bf16 buffers.
// ---------------------------------------------------------------------------
__global__ __launch_bounds__(512)
void gemm_qkv_kernel(const u16* __restrict__ qbf, const u16* __restrict__ kbf,
                     const u16* __restrict__ vbf,
                     const u16* __restrict__ WqT, const u16* __restrict__ WkT,
                     const u16* __restrict__ WvT,
                     const float* __restrict__ bq, const float* __restrict__ bk,
                     const float* __restrict__ bv,
                     float* __restrict__ res, u16* __restrict__ kpb,
                     u16* __restrict__ vpb)
{
    __shared__ u16 Al[4 * 128 * 8];
    __shared__ u16 Bl[4 * 128 * 8];
    const int z = blockIdx.z;
    const u16* A    = z == 0 ? qbf : z == 1 ? kbf : vbf;
    const u16* Bt   = z == 0 ? WqT : z == 1 ? WkT : WvT;
    const float* bb = z == 0 ? bq  : z == 1 ? bk  : bv;
    const bool obf  = z != 0;
    u16* ob   = z == 1 ? kpb : vpb;

    const int t = threadIdx.x;
    const int w = t >> 6, l = t & 63;
    const int m0 = blockIdx.x * 128, n0 = blockIdx.y * 128;
    const int sg = w & 3, sr = (w >> 2) * 64;
    const int wm = w >> 2, wn = w & 3;

    const u16* Ap = A  + (size_t)(m0 + sr + l) * DM + sg * 8;
    const u16* Bp = Bt + (size_t)(n0 + sr + l) * DM + sg * 8;
    u16* Alp = &Al[(sg * 128 + sr + l) * 8];
    u16* Blp = &Bl[(sg * 128 + sr + l) * 8];

    f32x4 acc[4][2];
    #pragma unroll
    for (int mi = 0; mi < 4; ++mi)
        #pragma unroll
        for (int ni = 0; ni < 2; ++ni)
            acc[mi][ni] = {0.f, 0.f, 0.f, 0.f};

    for (int kb = 0; kb < DM / 32; ++kb) {
        __syncthreads();
        GLOAD16(Ap + kb * 32, Alp);
        GLOAD16(Bp + kb * 32, Blp);
        __syncthreads();
        bf16x8 af[4], bfr[2];
        #pragma unroll
        for (int mi = 0; mi < 4; ++mi)
            af[mi] = *(const bf16x8*)&Al[((l >> 4) * 128 + wm * 64 + mi * 16 + (l & 15)) * 8];
        #pragma unroll
        for (int ni = 0; ni < 2; ++ni)
            bfr[ni] = *(const bf16x8*)&Bl[((l >> 4) * 128 + wn * 32 + ni * 16 + (l & 15)) * 8];
        #pragma unroll
        for (int mi = 0; mi < 4; ++mi)
            #pragma unroll
            for (int ni = 0; ni < 2; ++ni)
                acc[mi][ni] = __builtin_amdgcn_mfma_f32_16x16x32_bf16(af[mi], bfr[ni], acc[mi][ni], 0, 0, 0);
    }

    const int cq = l >> 4, cr = l & 15;
    #pragma unroll
    for (int mi = 0; mi < 4; ++mi) {
        const int row = m0 + wm * 64 + mi * 16 + cq * 4;
        #pragma unroll
        for (int ni = 0; ni < 2; ++ni) {
            const int col = n0 + wn * 32 + ni * 16 + cr;
            const float bbv = bb[col];
            #pragma unroll
            for (int j = 0; j < 4; ++j) {
                float vv = acc[mi][ni][j] + bbv;
                if (obf) ob[(size_t)(row + j) * DM + col] = f2b(vv);
                else     res[(size_t)(row + j) * DM + col] = vv;
            }
        }
    }
}

// ---------------------------------------------------------------------------
// MFMA flash attention (round-7/10 verified): swapped-operand 32x32x16,
// fixed-offset softmax, K+V ping-pong LDS, per-wave P^T LDS, s_setprio.
// ---------------------------------------------------------------------------
__global__ __launch_bounds__(256, 3)
void attn_mfma_kernel(const u16* __restrict__ qn, const u16* __restrict__ kn,
                      const u16* __restrict__ vt, u16* __restrict__ ab)
{
    __shared__ u16 Kl[2][8 * 64 * 8];
    __shared__ u16 Vl[2][8 * 64 * 8];
    __shared__ u16 Pl[4][8 * 32 * 8];

    const int t = threadIdx.x;
    const int w = t >> 6, l = t & 63;
    const int hi = l >> 5, ln = l & 31;

    const int bid = blockIdx.x;
    const int slot = bid >> 3;
    const int bh = (bid & 7) + 8 * (slot & 7);
    const int qt = slot >> 3;
    const int b = bh >> 3, h = bh & 7;

    const size_t bbase = (size_t)b * LQ * DM + h * HD;
    const int q0 = qt * 128 + w * 32;

    bf16x8 qf[4];
    {
        const u16* qp = qn + bbase + (size_t)(q0 + ln) * DM + hi * 8;
        #pragma unroll
        for (int c = 0; c < 4; ++c)
            qf[c] = *(const bf16x8*)(qp + c * 16);
    }

    const u16* Kg = kn + bbase + (size_t)(t & 63) * DM + (t >> 6) * 8;
    const u16* Vg = vt + (((size_t)bh * HD + (t >> 3)) << 10) + (t & 7) * 8;
    const int svu1 = ((t & 7) * 64 + (t >> 3)) * 8;
    const int svu2 = ((t & 7) * 64 + 32 + (t >> 3)) * 8;
    u16* Pw = &Pl[w][0];

    f32x16 oa0, oa1;
    #pragma unroll
    for (int r = 0; r < 16; ++r) { oa0[r] = 0.f; oa1[r] = 0.f; }
    float lsum = 0.f;

    *(uint4*)&Kl[0][t * 8]         = *(const uint4*)Kg;
    *(uint4*)&Kl[0][(t + 256) * 8] = *(const uint4*)(Kg + 32);
    *(uint4*)&Vl[0][svu1]          = *(const uint4*)Vg;
    *(uint4*)&Vl[0][svu2]          = *(const uint4*)(Vg + (32 << 10));
    uint4 ka1 = *(const uint4*)(Kg + (size_t)64 * DM);
    uint4 ka2 = *(const uint4*)(Kg + (size_t)64 * DM + 32);
    uint4 va1 = *(const uint4*)(Vg + 64);
    uint4 va2 = *(const uint4*)(Vg + (32 << 10) + 64);
    int cur = 0;

    for (int kt = 0; kt < 16; ++kt) {
        __syncthreads();

        f32x16 sa0, sa1;
        #pragma unroll
        for (int r = 0; r < 16; ++r) { sa0[r] = -SOFF; sa1[r] = -SOFF; }
        __builtin_amdgcn_s_setprio(1);
        #pragma unroll
        for (int c = 0; c < 4; ++c) {
            bf16x8 k0 = *(const bf16x8*)&Kl[cur][((c * 2 + hi) * 64 + ln) * 8];
            bf16x8 k1 = *(const bf16x8*)&Kl[cur][((c * 2 + hi) * 64 + 32 + ln) * 8];
            sa0 = __builtin_amdgcn_mfma_f32_32x32x16_bf16(k0, qf[c], sa0, 0, 0, 0);
            sa1 = __builtin_amdgcn_mfma_f32_32x32x16_bf16(k1, qf[c], sa1, 0, 0, 0);
        }
        __builtin_amdgcn_s_setprio(0);

        if (kt < 15) {
            *(uint4*)&Kl[cur ^ 1][t * 8]         = ka1;
            *(uint4*)&Kl[cur ^ 1][(t + 256) * 8] = ka2;
            *(uint4*)&Vl[cur ^ 1][svu1]          = va1;
            *(uint4*)&Vl[cur ^ 1][svu2]          = va2;
            if (kt < 14) {
                ka1 = *(const uint4*)(Kg + (size_t)(kt + 2) * 64 * DM);
                ka2 = *(const uint4*)(Kg + (size_t)(kt + 2) * 64 * DM + 32);
                va1 = *(const uint4*)(Vg + (kt + 2) * 64);
                va2 = *(const uint4*)(Vg + (32 << 10) + (kt + 2) * 64);
            }
        }

        #pragma unroll
        for (int r = 0; r < 16; ++r) {
            sa0[r] = __builtin_amdgcn_exp2f(sa0[r]);
            sa1[r] = __builtin_amdgcn_exp2f(sa1[r]);
            lsum += sa0[r] + sa1[r];
        }

        #pragma unroll
        for (int g0 = 0; g0 < 4; ++g0) {
            uint2 w0, w1;
            w0.x = pk2(sa0[4 * g0],     sa0[4 * g0 + 1]);
            w0.y = pk2(sa0[4 * g0 + 2], sa0[4 * g0 + 3]);
            w1.x = pk2(sa1[4 * g0],     sa1[4 * g0 + 1]);
            w1.y = pk2(sa1[4 * g0 + 2], sa1[4 * g0 + 3]);
            *(uint2*)&Pw[(g0 * 32 + ln) * 8 + 4 * hi]       = w0;
            *(uint2*)&Pw[((g0 + 4) * 32 + ln) * 8 + 4 * hi] = w1;
        }

        __builtin_amdgcn_s_setprio(1);
        #pragma unroll
        for (int ks = 0; ks < 4; ++ks) {
            bf16x8 pa = *(const bf16x8*)&Pw[((ks * 2 + hi) * 32 + ln) * 8];
            bf16x8 v0 = *(const bf16x8*)&Vl[cur][((ks * 2 + hi) * 64 + ln) * 8];
            bf16x8 v1 = *(const bf16x8*)&Vl[cur][((ks * 2 + hi) * 64 + 32 + ln) * 8];
            oa0 = __builtin_amdgcn_mfma_f32_32x32x16_bf16(v0, pa, oa0, 0, 0, 0);
            oa1 = __builtin_amdgcn_mfma_f32_32x32x16_bf16(v1, pa, oa1, 0, 0, 0);
        }
        __builtin_amdgcn_s_setprio(0);
        cur ^= 1;
    }

    lsum += __shfl_xor(lsum, 32, 64);
    const float rinv = 1.f / lsum;
    u16* op = ab + (size_t)(b * LQ + q0 + ln) * DM + h * HD;
    #pragma unroll
    for (int g = 0; g < 4; ++g) {
        uint2 s0, s1;
        s0.x = pk2(oa0[4 * g] * rinv, oa0[4 * g + 1] * rinv);
        s0.y = pk2(oa0[4 * g + 2] * rinv, oa0[4 * g + 3] * rinv);
        s1.x = pk2(oa1[4 * g] * rinv, oa1[4 * g + 1] * rinv);
        s1.y = pk2(oa1[4 * g + 2] * rinv, oa1[4 * g + 3] * rinv);
        *(uint2*)(op + 8 * g + 4 * hi)      = s0;
        *(uint2*)(op + 32 + 8 * g + 4 * hi) = s1;
    }
}

// ---------------------------------------------------------------------------
extern "C" void kernel_launch(void* const* d_in, const int* in_sizes, int n_in,
                              void* d_out, int out_size, void* d_ws, size_t ws_size,
                              hipStream_t stream)
{
    const float* q    = (const float*)d_in[0];
    const float* k    = (const float*)d_in[1];
    const float* v    = (const float*)d_in[2];
    const float* Wq   = (const float*)d_in[3];
    const float* bq   = (const float*)d_in[4];
    const float* Wk   = (const float*)d_in[5];
    const float* bk   = (const float*)d_in[6];
    const float* Wv   = (const float*)d_in[7];
    const float* bv   = (const float*)d_in[8];
    const float* g_q  = (const float*)d_in[9];
    const float* be_q = (const float*)d_in[10];
    const float* g_k  = (const float*)d_in[11];
    const float* be_k = (const float*)d_in[12];
    const float* g_v  = (const float*)d_in[13];
    const float* be_v = (const float*)d_in[14];
    const float* W1   = (const float*)d_in[15];
    const float* b1   = (const float*)d_in[16];
    const float* W2   = (const float*)d_in[17];
    const float* b2   = (const float*)d_in[18];

    float* outp = (float*)d_out;
    float* res  = outp + (size_t)NR * DM;       // residual = raw qp (f32)

    char* wsb = (char*)d_ws;
    const size_t MB = 1024 * 1024;
    u16* kpb = (u16*)(wsb);                     // 8 MB: bf16 kp (pre-LN)
    u16* vpb = (u16*)(wsb + 8 * MB);            // 8 MB: bf16 vp (pre-LN)
    u16* hbb = (u16*)(wsb + 16 * MB);           // 8 MB: FFN hidden (bf16)
    u16* vtb = (u16*)(wsb + 24 * MB);           // 8 MB: V^T (post-LN)
    u16* qbf = (u16*)(wsb + 32 * MB);           // 8 MB: bf16(q), later qn
    u16* kbf = (u16*)(wsb + 40 * MB);           // 8 MB: bf16(k), later kn
    u16* vbf = (u16*)(wsb + 48 * MB);           // 8 MB: bf16(v) conv only
    u16* WqT = (u16*)(wsb + 56 * MB);
    u16* WkT = WqT + 512 * 512;
    u16* WvT = WkT + 512 * 512;
    u16* W1T = WvT + 512 * 512;
    u16* W2T = W1T + 512 * 512;
    u16* abb = (u16*)wsb;                       // attn out reuses kpb (dead after ln)

    prep_kernel<<<6464, 256, 0, stream>>>(q, k, v, qbf, kbf, vbf,
                                          Wq, Wk, Wv, W1, W2,
                                          WqT, WkT, WvT, W1T, W2T);

    gemm_qkv_kernel<<<dim3(NR / 128, DM / 128, 3), 512, 0, stream>>>(
        qbf, kbf, vbf, WqT, WkT, WvT, bq, bk, bv, res, kpb, vpb);

    ln_all_kernel<<<16384 + 128, 256, 0, stream>>>(res, kpb, vpb,
                                                   g_q, be_q, g_k, be_k, g_v, be_v,
                                                   qbf, kbf, vtb);

    attn_mfma_kernel<<<512, 256, 0, stream>>>(qbf, kbf, vtb, abb);

    dim3 gg(NR / 128, DM / 128);
    mfma_gemm_kernel<true,  true ><<<gg, 512, 0, stream>>>(abb, W1T, b1, (void*)hbb);
    mfma_gemm_kernel<false, false><<<gg, 512, 0, stream>>>(hbb, W2T, b2, (void*)outp);
}

// Round 17
// 122.572 us; speedup vs baseline: 1.0766x; 1.0766x over previous
//
#include <hip/hip_runtime.h>
#include <hip/hip_bf16.h>
#include <stdint.h>

typedef unsigned short u16;
typedef __attribute__((ext_vector_type(8))) short bf16x8;
typedef __attribute__((ext_vector_type(4))) float f32x4;
typedef __attribute__((ext_vector_type(16))) float f32x16;

#define NR 8192     // B*L rows
#define DM 512      // model dim
#define NH 8
#define HD 64
#define LQ 1024

// fold 1/sqrt(64) * log2(e) into LN-q so scores are in exp2 domain
#define QSCALE (0.125f * 1.4426950408889634f)
// fixed softmax offset (safe: |s| <= 512*0.125*log2e = 92 by Cauchy-Schwarz)
#define SOFF 16.0f

__device__ __forceinline__ u16 f2b(float f) {
    union { float f; uint32_t u; } v; v.f = f;
    uint32_t r = v.u + 0x7fffu + ((v.u >> 16) & 1u);   // RNE
    return (u16)(r >> 16);
}
// packed f32x2 -> bf16x2 (v_cvt_pk_bf16_f32, RNE)
__device__ __forceinline__ uint32_t pk2(float lo, float hi) {
    __hip_bfloat162 h = __float22bfloat162_rn(make_float2(lo, hi));
    union { __hip_bfloat162 h; uint32_t u; } c; c.h = h;
    return c.u;
}
__device__ __forceinline__ float b2f(uint32_t lo16) {
    union { uint32_t u; float f; } c; c.u = lo16 << 16; return c.f;
}

// ---------------------------------------------------------------------------
// prep: fused conv3 (blocks 0..6143) + wt5 transpose (blocks 6144..6463)
// ---------------------------------------------------------------------------
__global__ __launch_bounds__(256)
void prep_kernel(const float* __restrict__ q, const float* __restrict__ k,
                 const float* __restrict__ v, u16* __restrict__ qo,
                 u16* __restrict__ ko, u16* __restrict__ vo,
                 const float* __restrict__ W0, const float* __restrict__ W1,
                 const float* __restrict__ W2, const float* __restrict__ W3,
                 const float* __restrict__ W4,
                 u16* __restrict__ T0, u16* __restrict__ T1, u16* __restrict__ T2,
                 u16* __restrict__ T3, u16* __restrict__ T4)
{
    __shared__ float S[64][65];
    const int bid = blockIdx.x;
    if (bid < 6144) {
        const int y = bid >> 11, x = bid & 2047;
        const float* in = y == 0 ? q : y == 1 ? k : v;
        u16* out = y == 0 ? qo : y == 1 ? ko : vo;
        const int i = x * 256 + threadIdx.x;
        const float4* p = (const float4*)in + (size_t)i * 2;
        float4 a = p[0], b = p[1];
        uint4 o;
        o.x = pk2(a.x, a.y);
        o.y = pk2(a.z, a.w);
        o.z = pk2(b.x, b.y);
        o.w = pk2(b.z, b.w);
        ((uint4*)out)[i] = o;
    } else {
        const int id = bid - 6144;
        const int z = id >> 6, idx = id & 63;
        const float* W = z == 0 ? W0 : z == 1 ? W1 : z == 2 ? W2 : z == 3 ? W3 : W4;
        u16* Wt = z == 0 ? T0 : z == 1 ? T1 : z == 2 ? T2 : z == 3 ? T3 : T4;
        const int k0 = (idx >> 3) * 64, n0 = (idx & 7) * 64;
        #pragma unroll
        for (int p = 0; p < 16; ++p) {
            int i = threadIdx.x + p * 256;
            int r = i >> 6, c = i & 63;
            S[r][c] = W[(size_t)(k0 + r) * DM + n0 + c];
        }
        __syncthreads();
        #pragma unroll
        for (int p = 0; p < 16; ++p) {
            int i = threadIdx.x + p * 256;
            int r = i >> 6, c = i & 63;
            Wt[(size_t)(n0 + r) * DM + k0 + c] = f2b(S[c][r]);
        }
    }
}

// ---------------------------------------------------------------------------
// ln_all (round-10 verified): blocks 0..16383 row LN q/k; 16384..16511
// v LN + per-head transpose -> vtb[b][h][d][l].
// ---------------------------------------------------------------------------
__global__ __launch_bounds__(256)
void ln_all_kernel(const float* __restrict__ res, const u16* __restrict__ kpb,
                   const u16* __restrict__ vpb,
                   const float* __restrict__ gq, const float* __restrict__ bq,
                   const float* __restrict__ gk, const float* __restrict__ bk,
                   const float* __restrict__ gv, const float* __restrict__ bv,
                   u16* __restrict__ oq, u16* __restrict__ ok,
                   u16* __restrict__ vtb)
{
    __shared__ float ss[4], ss2[4];
    __shared__ u16 S[64][82];
    __shared__ float stats[64][2];
    __shared__ float gb_[512], bb_[512];

    const int bid = blockIdx.x;
    const int t = threadIdx.x;

    if (bid < 16384) {
        const int y = bid >> 13;            // 0=q, 1=k
        const int row = bid & 8191;
        const float* gm = y == 0 ? gq : gk;
        const float* be = y == 0 ? bq : bk;
        u16* out = y == 0 ? oq : ok;
        const float scale = y == 0 ? QSCALE : 1.f;

        const size_t off = (size_t)row * DM + t * 2;
        float vx, vy;
        if (y == 0) {
            float2 v = *(const float2*)(res + off);
            vx = v.x; vy = v.y;
        } else {
            uint32_t u = *(const uint32_t*)(kpb + off);
            vx = b2f(u & 0xffffu); vy = b2f(u >> 16);
        }
        float s = vx + vy, s2 = vx * vx + vy * vy;
        #pragma unroll
        for (int o = 32; o; o >>= 1) { s += __shfl_down(s, o); s2 += __shfl_down(s2, o); }
        if ((t & 63) == 0) { ss[t >> 6] = s; ss2[t >> 6] = s2; }
        __syncthreads();
        float Sm = ss[0] + ss[1] + ss[2] + ss[3];
        float S2m = ss2[0] + ss2[1] + ss2[2] + ss2[3];
        float mu = Sm * (1.f / DM);
        float var = S2m * (1.f / DM) - mu * mu;
        float rs = rsqrtf(var + 1e-6f);
        float g0 = gm[t * 2] * scale, g1 = gm[t * 2 + 1] * scale;
        float b0 = be[t * 2] * scale, b1 = be[t * 2 + 1] * scale;
        float o0 = (vx - mu) * rs * g0 + b0;
        float o1 = (vy - mu) * rs * g1 + b1;
        *(uint32_t*)(out + off) = pk2(o0, o1);
        return;
    }

    // ---- v LN + transpose tile
    const int id = bid - 16384;
    const int lt = id & 15, b = id >> 4;

    gb_[t]       = gv[t];
    gb_[t + 256] = gv[t + 256];
    bb_[t]       = bv[t];
    bb_[t + 256] = bv[t + 256];

    // phase 1: row stats (4 lanes per row, interleaved 32-col chunks)
    {
        const int r = t >> 2, qd = t & 3;
        const u16* src = vpb + ((size_t)(b * LQ + lt * 64 + r)) * DM + qd * 8;
        float s = 0.f, s2 = 0.f;
        #pragma unroll
        for (int p = 0; p < 16; ++p) {
            uint4 x = *(const uint4*)(src + p * 32);
            const uint32_t xs[4] = {x.x, x.y, x.z, x.w};
            #pragma unroll
            for (int e = 0; e < 4; ++e) {
                float f0 = b2f(xs[e] & 0xffffu), f1 = b2f(xs[e] >> 16);
                s += f0 + f1; s2 += f0 * f0 + f1 * f1;
            }
        }
        s  += __shfl_xor(s, 1);  s  += __shfl_xor(s, 2);
        s2 += __shfl_xor(s2, 1); s2 += __shfl_xor(s2, 2);
        if (qd == 0) {
            float mu = s * (1.f / DM);
            float var = s2 * (1.f / DM) - mu * mu;
            stats[r][0] = mu;
            stats[r][1] = rsqrtf(var + 1e-6f);
        }
    }
    __syncthreads();

    // phase 2: per head, normalize into S then transpose-write to vtb
    for (int h = 0; h < NH; ++h) {
        {
            const int rr = t >> 2, dc = (t & 3) * 16;
            const u16* sp = vpb + ((size_t)(b * LQ + lt * 64 + rr)) * DM + h * 64 + dc;
            uint4 a = *(const uint4*)sp;
            uint4 b4 = *(const uint4*)(sp + 8);
            const float mu = stats[rr][0], rs = stats[rr][1];
            const uint32_t xs[8] = {a.x, a.y, a.z, a.w, b4.x, b4.y, b4.z, b4.w};
            #pragma unroll
            for (int e = 0; e < 8; ++e) {
                const int c = h * 64 + dc + e * 2;
                float f0 = (b2f(xs[e] & 0xffffu) - mu) * rs * gb_[c]     + bb_[c];
                float f1 = (b2f(xs[e] >> 16)     - mu) * rs * gb_[c + 1] + bb_[c + 1];
                *(uint32_t*)&S[rr][dc + e * 2] = pk2(f0, f1);
            }
        }
        __syncthreads();
        {
            const int d = t >> 2, lc = (t & 3) * 16;
            u16 tmp[16];
            #pragma unroll
            for (int e = 0; e < 16; ++e) tmp[e] = S[lc + e][d];
            u16* dst = vtb + (((size_t)(b * NH + h) * HD + d) << 10) + lt * 64 + lc;
            *(uint4*)dst       = *(uint4*)&tmp[0];
            *(uint4*)(dst + 8) = *(uint4*)&tmp[8];
        }
        __syncthreads();
    }
}

// ---------------------------------------------------------------------------
// bf16 MFMA GEMM body (rounds 2-10 verified, reg-staged early prefetch):
// C[M,512] = A*Bt^T (+bias)(+relu). 128x128 tile, 512 threads = 8 waves.
// ---------------------------------------------------------------------------
template<bool RELU, bool OUT_BF16>
__device__ __forceinline__
void gemm_body(const u16* __restrict__ A, const u16* __restrict__ Bt,
               const float* __restrict__ bias, void* __restrict__ Cout)
{
    __shared__ u16 Al[4 * 128 * 8];
    __shared__ u16 Bl[4 * 128 * 8];
    const int t = threadIdx.x;
    const int w = t >> 6, l = t & 63;
    const int m0 = blockIdx.x * 128, n0 = blockIdx.y * 128;
    const int sg = w & 3, sr = (w >> 2) * 64;
    const int wm = w >> 2, wn = w & 3;

    const u16* Ap = A  + (size_t)(m0 + sr + l) * DM + sg * 8;
    const u16* Bp = Bt + (size_t)(n0 + sr + l) * DM + sg * 8;
    const int su = (sg * 128 + sr + l) * 8;

    uint4 ga = *(const uint4*)Ap;
    uint4 gb = *(const uint4*)Bp;

    f32x4 acc[4][2];
    #pragma unroll
    for (int mi = 0; mi < 4; ++mi)
        #pragma unroll
        for (int ni = 0; ni < 2; ++ni)
            acc[mi][ni] = {0.f, 0.f, 0.f, 0.f};

    for (int kb = 0; kb < DM / 32; ++kb) {
        __syncthreads();
        *(uint4*)&Al[su] = ga;
        *(uint4*)&Bl[su] = gb;
        if (kb + 1 < DM / 32) {
            ga = *(const uint4*)(Ap + (kb + 1) * 32);
            gb = *(const uint4*)(Bp + (kb + 1) * 32);
        }
        __syncthreads();
        bf16x8 af[4], bfr[2];
        #pragma unroll
        for (int mi = 0; mi < 4; ++mi)
            af[mi] = *(const bf16x8*)&Al[((l >> 4) * 128 + wm * 64 + mi * 16 + (l & 15)) * 8];
        #pragma unroll
        for (int ni = 0; ni < 2; ++ni)
            bfr[ni] = *(const bf16x8*)&Bl[((l >> 4) * 128 + wn * 32 + ni * 16 + (l & 15)) * 8];
        #pragma unroll
        for (int mi = 0; mi < 4; ++mi)
            #pragma unroll
            for (int ni = 0; ni < 2; ++ni)
                acc[mi][ni] = __builtin_amdgcn_mfma_f32_16x16x32_bf16(af[mi], bfr[ni], acc[mi][ni], 0, 0, 0);
    }

    const int cq = l >> 4, cr = l & 15;
    #pragma unroll
    for (int mi = 0; mi < 4; ++mi) {
        const int row = m0 + wm * 64 + mi * 16 + cq * 4;
        #pragma unroll
        for (int ni = 0; ni < 2; ++ni) {
            const int col = n0 + wn * 32 + ni * 16 + cr;
            const float bb = bias[col];
            #pragma unroll
            for (int j = 0; j < 4; ++j) {
                float vv = acc[mi][ni][j] + bb;
                if (RELU) vv = fmaxf(vv, 0.f);
                if (OUT_BF16) ((u16*)Cout)[(size_t)(row + j) * DM + col] = f2b(vv);
                else          ((float*)Cout)[(size_t)(row + j) * DM + col] = vv;
            }
        }
    }
}

template<bool RELU, bool OUT_BF16>
__global__ __launch_bounds__(512)
void mfma_gemm_kernel(const u16* __restrict__ A, const u16* __restrict__ Bt,
                      const float* __restrict__ bias, void* __restrict__ Cout)
{
    gemm_body<RELU, OUT_BF16>(A, Bt, bias, Cout);
}

// ---------------------------------------------------------------------------
// fused q/k/v projection GEMM, grid (64, 4, 3), reg-staged body.
// q writes f32 res (residual output); k/v write bf16 buffers.
// ---------------------------------------------------------------------------
__global__ __launch_bounds__(512)
void gemm_qkv_kernel(const u16* __restrict__ qbf, const u16* __restrict__ kbf,
                     const u16* __restrict__ vbf,
                     const u16* __restrict__ WqT, const u16* __restrict__ WkT,
                     const u16* __restrict__ WvT,
                     const float* __restrict__ bq, const float* __restrict__ bk,
                     const float* __restrict__ bv,
                     float* __restrict__ res, u16* __restrict__ kpb,
                     u16* __restrict__ vpb)
{
    __shared__ u16 Al[4 * 128 * 8];
    __shared__ u16 Bl[4 * 128 * 8];
    const int z = blockIdx.z;
    const u16* A    = z == 0 ? qbf : z == 1 ? kbf : vbf;
    const u16* Bt   = z == 0 ? WqT : z == 1 ? WkT : WvT;
    const float* bb = z == 0 ? bq  : z == 1 ? bk  : bv;
    const bool obf  = z != 0;
    u16* ob   = z == 1 ? kpb : vpb;

    const int t = threadIdx.x;
    const int w = t >> 6, l = t & 63;
    const int m0 = blockIdx.x * 128, n0 = blockIdx.y * 128;
    const int sg = w & 3, sr = (w >> 2) * 64;
    const int wm = w >> 2, wn = w & 3;

    const u16* Ap = A  + (size_t)(m0 + sr + l) * DM + sg * 8;
    const u16* Bp = Bt + (size_t)(n0 + sr + l) * DM + sg * 8;
    const int su = (sg * 128 + sr + l) * 8;

    uint4 ga = *(const uint4*)Ap;
    uint4 gb = *(const uint4*)Bp;

    f32x4 acc[4][2];
    #pragma unroll
    for (int mi = 0; mi < 4; ++mi)
        #pragma unroll
        for (int ni = 0; ni < 2; ++ni)
            acc[mi][ni] = {0.f, 0.f, 0.f, 0.f};

    for (int kb = 0; kb < DM / 32; ++kb) {
        __syncthreads();
        *(uint4*)&Al[su] = ga;
        *(uint4*)&Bl[su] = gb;
        if (kb + 1 < DM / 32) {
            ga = *(const uint4*)(Ap + (kb + 1) * 32);
            gb = *(const uint4*)(Bp + (kb + 1) * 32);
        }
        __syncthreads();
        bf16x8 af[4], bfr[2];
        #pragma unroll
        for (int mi = 0; mi < 4; ++mi)
            af[mi] = *(const bf16x8*)&Al[((l >> 4) * 128 + wm * 64 + mi * 16 + (l & 15)) * 8];
        #pragma unroll
        for (int ni = 0; ni < 2; ++ni)
            bfr[ni] = *(const bf16x8*)&Bl[((l >> 4) * 128 + wn * 32 + ni * 16 + (l & 15)) * 8];
        #pragma unroll
        for (int mi = 0; mi < 4; ++mi)
            #pragma unroll
            for (int ni = 0; ni < 2; ++ni)
                acc[mi][ni] = __builtin_amdgcn_mfma_f32_16x16x32_bf16(af[mi], bfr[ni], acc[mi][ni], 0, 0, 0);
    }

    const int cq = l >> 4, cr = l & 15;
    #pragma unroll
    for (int mi = 0; mi < 4; ++mi) {
        const int row = m0 + wm * 64 + mi * 16 + cq * 4;
        #pragma unroll
        for (int ni = 0; ni < 2; ++ni) {
            const int col = n0 + wn * 32 + ni * 16 + cr;
            const float bbv = bb[col];
            #pragma unroll
            for (int j = 0; j < 4; ++j) {
                float vv = acc[mi][ni][j] + bbv;
                if (obf) ob[(size_t)(row + j) * DM + col] = f2b(vv);
                else     res[(size_t)(row + j) * DM + col] = vv;
            }
        }
    }
}

// ---------------------------------------------------------------------------
// MFMA flash attention (round-7/10 verified): swapped-operand 32x32x16,
// fixed-offset softmax, K+V ping-pong LDS, per-wave P^T LDS, s_setprio.
// ---------------------------------------------------------------------------
__global__ __launch_bounds__(256, 3)
void attn_mfma_kernel(const u16* __restrict__ qn, const u16* __restrict__ kn,
                      const u16* __restrict__ vt, u16* __restrict__ ab)
{
    __shared__ u16 Kl[2][8 * 64 * 8];
    __shared__ u16 Vl[2][8 * 64 * 8];
    __shared__ u16 Pl[4][8 * 32 * 8];

    const int t = threadIdx.x;
    const int w = t >> 6, l = t & 63;
    const int hi = l >> 5, ln = l & 31;

    const int bid = blockIdx.x;
    const int slot = bid >> 3;
    const int bh = (bid & 7) + 8 * (slot & 7);
    const int qt = slot >> 3;
    const int b = bh >> 3, h = bh & 7;

    const size_t bbase = (size_t)b * LQ * DM + h * HD;
    const int q0 = qt * 128 + w * 32;

    bf16x8 qf[4];
    {
        const u16* qp = qn + bbase + (size_t)(q0 + ln) * DM + hi * 8;
        #pragma unroll
        for (int c = 0; c < 4; ++c)
            qf[c] = *(const bf16x8*)(qp + c * 16);
    }

    const u16* Kg = kn + bbase + (size_t)(t & 63) * DM + (t >> 6) * 8;
    const u16* Vg = vt + (((size_t)bh * HD + (t >> 3)) << 10) + (t & 7) * 8;
    const int svu1 = ((t & 7) * 64 + (t >> 3)) * 8;
    const int svu2 = ((t & 7) * 64 + 32 + (t >> 3)) * 8;
    u16* Pw = &Pl[w][0];

    f32x16 oa0, oa1;
    #pragma unroll
    for (int r = 0; r < 16; ++r) { oa0[r] = 0.f; oa1[r] = 0.f; }
    float lsum = 0.f;

    *(uint4*)&Kl[0][t * 8]         = *(const uint4*)Kg;
    *(uint4*)&Kl[0][(t + 256) * 8] = *(const uint4*)(Kg + 32);
    *(uint4*)&Vl[0][svu1]          = *(const uint4*)Vg;
    *(uint4*)&Vl[0][svu2]          = *(const uint4*)(Vg + (32 << 10));
    uint4 ka1 = *(const uint4*)(Kg + (size_t)64 * DM);
    uint4 ka2 = *(const uint4*)(Kg + (size_t)64 * DM + 32);
    uint4 va1 = *(const uint4*)(Vg + 64);
    uint4 va2 = *(const uint4*)(Vg + (32 << 10) + 64);
    int cur = 0;

    for (int kt = 0; kt < 16; ++kt) {
        __syncthreads();

        f32x16 sa0, sa1;
        #pragma unroll
        for (int r = 0; r < 16; ++r) { sa0[r] = -SOFF; sa1[r] = -SOFF; }
        __builtin_amdgcn_s_setprio(1);
        #pragma unroll
        for (int c = 0; c < 4; ++c) {
            bf16x8 k0 = *(const bf16x8*)&Kl[cur][((c * 2 + hi) * 64 + ln) * 8];
            bf16x8 k1 = *(const bf16x8*)&Kl[cur][((c * 2 + hi) * 64 + 32 + ln) * 8];
            sa0 = __builtin_amdgcn_mfma_f32_32x32x16_bf16(k0, qf[c], sa0, 0, 0, 0);
            sa1 = __builtin_amdgcn_mfma_f32_32x32x16_bf16(k1, qf[c], sa1, 0, 0, 0);
        }
        __builtin_amdgcn_s_setprio(0);

        if (kt < 15) {
            *(uint4*)&Kl[cur ^ 1][t * 8]         = ka1;
            *(uint4*)&Kl[cur ^ 1][(t + 256) * 8] = ka2;
            *(uint4*)&Vl[cur ^ 1][svu1]          = va1;
            *(uint4*)&Vl[cur ^ 1][svu2]          = va2;
            if (kt < 14) {
                ka1 = *(const uint4*)(Kg + (size_t)(kt + 2) * 64 * DM);
                ka2 = *(const uint4*)(Kg + (size_t)(kt + 2) * 64 * DM + 32);
                va1 = *(const uint4*)(Vg + (kt + 2) * 64);
                va2 = *(const uint4*)(Vg + (32 << 10) + (kt + 2) * 64);
            }
        }

        #pragma unroll
        for (int r = 0; r < 16; ++r) {
            sa0[r] = __builtin_amdgcn_exp2f(sa0[r]);
            sa1[r] = __builtin_amdgcn_exp2f(sa1[r]);
            lsum += sa0[r] + sa1[r];
        }

        #pragma unroll
        for (int g0 = 0; g0 < 4; ++g0) {
            uint2 w0, w1;
            w0.x = pk2(sa0[4 * g0],     sa0[4 * g0 + 1]);
            w0.y = pk2(sa0[4 * g0 + 2], sa0[4 * g0 + 3]);
            w1.x = pk2(sa1[4 * g0],     sa1[4 * g0 + 1]);
            w1.y = pk2(sa1[4 * g0 + 2], sa1[4 * g0 + 3]);
            *(uint2*)&Pw[(g0 * 32 + ln) * 8 + 4 * hi]       = w0;
            *(uint2*)&Pw[((g0 + 4) * 32 + ln) * 8 + 4 * hi] = w1;
        }

        __builtin_amdgcn_s_setprio(1);
        #pragma unroll
        for (int ks = 0; ks < 4; ++ks) {
            bf16x8 pa = *(const bf16x8*)&Pw[((ks * 2 + hi) * 32 + ln) * 8];
            bf16x8 v0 = *(const bf16x8*)&Vl[cur][((ks * 2 + hi) * 64 + ln) * 8];
            bf16x8 v1 = *(const bf16x8*)&Vl[cur][((ks * 2 + hi) * 64 + 32 + ln) * 8];
            oa0 = __builtin_amdgcn_mfma_f32_32x32x16_bf16(v0, pa, oa0, 0, 0, 0);
            oa1 = __builtin_amdgcn_mfma_f32_32x32x16_bf16(v1, pa, oa1, 0, 0, 0);
        }
        __builtin_amdgcn_s_setprio(0);
        cur ^= 1;
    }

    lsum += __shfl_xor(lsum, 32, 64);
    const float rinv = 1.f / lsum;
    u16* op = ab + (size_t)(b * LQ + q0 + ln) * DM + h * HD;
    #pragma unroll
    for (int g = 0; g < 4; ++g) {
        uint2 s0, s1;
        s0.x = pk2(oa0[4 * g] * rinv, oa0[4 * g + 1] * rinv);
        s0.y = pk2(oa0[4 * g + 2] * rinv, oa0[4 * g + 3] * rinv);
        s1.x = pk2(oa1[4 * g] * rinv, oa1[4 * g + 1] * rinv);
        s1.y = pk2(oa1[4 * g + 2] * rinv, oa1[4 * g + 3] * rinv);
        *(uint2*)(op + 8 * g + 4 * hi)      = s0;
        *(uint2*)(op + 32 + 8 * g + 4 * hi) = s1;
    }
}

// ---------------------------------------------------------------------------
extern "C" void kernel_launch(void* const* d_in, const int* in_sizes, int n_in,
                              void* d_out, int out_size, void* d_ws, size_t ws_size,
                              hipStream_t stream)
{
    const float* q    = (const float*)d_in[0];
    const float* k    = (const float*)d_in[1];
    const float* v    = (const float*)d_in[2];
    const float* Wq   = (const float*)d_in[3];
    const float* bq   = (const float*)d_in[4];
    const float* Wk   = (const float*)d_in[5];
    const float* bk   = (const float*)d_in[6];
    const float* Wv   = (const float*)d_in[7];
    const float* bv   = (const float*)d_in[8];
    const float* g_q  = (const float*)d_in[9];
    const float* be_q = (const float*)d_in[10];
    const float* g_k  = (const float*)d_in[11];
    const float* be_k = (const float*)d_in[12];
    const float* g_v  = (const float*)d_in[13];
    const float* be_v = (const float*)d_in[14];
    const float* W1   = (const float*)d_in[15];
    const float* b1   = (const float*)d_in[16];
    const float* W2   = (const float*)d_in[17];
    const float* b2   = (const float*)d_in[18];

    float* outp = (float*)d_out;
    float* res  = outp + (size_t)NR * DM;       // residual = raw qp (f32)

    char* wsb = (char*)d_ws;
    const size_t MB = 1024 * 1024;
    u16* kpb = (u16*)(wsb);                     // 8 MB: bf16 kp (pre-LN)
    u16* vpb = (u16*)(wsb + 8 * MB);            // 8 MB: bf16 vp (pre-LN)
    u16* hbb = (u16*)(wsb + 16 * MB);           // 8 MB: FFN hidden (bf16)
    u16* vtb = (u16*)(wsb + 24 * MB);           // 8 MB: V^T (post-LN)
    u16* qbf = (u16*)(wsb + 32 * MB);           // 8 MB: bf16(q), later qn
    u16* kbf = (u16*)(wsb + 40 * MB);           // 8 MB: bf16(k), later kn
    u16* vbf = (u16*)(wsb + 48 * MB);           // 8 MB: bf16(v) conv only
    u16* WqT = (u16*)(wsb + 56 * MB);
    u16* WkT = WqT + 512 * 512;
    u16* WvT = WkT + 512 * 512;
    u16* W1T = WvT + 512 * 512;
    u16* W2T = W1T + 512 * 512;
    u16* abb = (u16*)wsb;                       // attn out reuses kpb (dead after ln)

    prep_kernel<<<6464, 256, 0, stream>>>(q, k, v, qbf, kbf, vbf,
                                          Wq, Wk, Wv, W1, W2,
                                          WqT, WkT, WvT, W1T, W2T);

    gemm_qkv_kernel<<<dim3(NR / 128, DM / 128, 3), 512, 0, stream>>>(
        qbf, kbf, vbf, WqT, WkT, WvT, bq, bk, bv, res, kpb, vpb);

    ln_all_kernel<<<16384 + 128, 256, 0, stream>>>(res, kpb, vpb,
                                                   g_q, be_q, g_k, be_k, g_v, be_v,
                                                   qbf, kbf, vtb);

    attn_mfma_kernel<<<512, 256, 0, stream>>>(qbf, kbf, vtb, abb);

    dim3 gg(NR / 128, DM / 128);
    mfma_gemm_kernel<true,  true ><<<gg, 512, 0, stream>>>(abb, W1T, b1, (void*)hbb);
    mfma_gemm_kernel<false, false><<<gg, 512, 0, stream>>>(hbb, W2T, b2, (void*)outp);
}